// Round 10
// baseline (1232.386 us; speedup 1.0000x reference)
//
#include <hip/hip_runtime.h>
#include <hip/hip_bf16.h>
#include <math.h>

// Pattern-aware MoE, MI355X. Sparse top-2 dispatch with bf16 MFMA grouped GEMMs.
// B=8 S=4096 D=512 H=2048 E=8 P=16 K=2.
// R12: gemm1 rebuilt as A-resident: the gathered token rows (the latency pole,
//   FETCH 280MB = 8x refetch at HBM latency exposed by every K-step barrier)
//   are staged ONCE per block into LDS (M=64 x K=512 = 64KB), then a 4-chunk
//   N-loop (512 cols each) streams only L2-hot B through the proven R3 2-buf
//   gl16 pipeline. 128KB LDS, 512thr/8 waves (each 64x64, acc 64 VGPR), one
//   barrier per K-step that now drains only a ~300cy L2 fetch issued a full
//   step earlier. A-LDS uses XOR-slot swizzle (src-permuted, linear dest,
//   swizzled read) -> 16 lanes/16 banks. gemm2 = R9 verbatim.

#define B_ 8
#define S_ 4096
#define D_ 512
#define H_ 2048
#define HH (H_ / 2)         // 1024 half width
#define E_ 8
#define P_ 16
#define NTOK (B_ * S_)      // 32768
#define NPAIR (NTOK * 2)    // 65536

typedef __bf16 bf16;
typedef __bf16 bf16x8 __attribute__((ext_vector_type(8)));
typedef float f32x4 __attribute__((ext_vector_type(4)));

// ---- workspace layout (bytes) ----
#define OFF_GATES 256
#define OFF_LIST (OFF_GATES + NPAIR * 4)
#define OFF_XBF (OFF_LIST + E_ * NTOK * 4)
#define OFF_W13T (OFF_XBF + (size_t)NTOK * D_ * 2)                // [E][2H][D] interleaved
#define OFF_W2T (OFF_W13T + (size_t)E_ * 2 * H_ * D_ * 2)
#define OFF_HBUF (OFF_W2T + (size_t)E_ * D_ * H_ * 2)
#define WS_NEEDED (OFF_HBUF + (size_t)NPAIR * HH * 2)  // ~209 MiB

// async global->LDS, 16B per lane; LDS dest = base + lane*16 (wave-uniform base)
__device__ __forceinline__ void gl16(const bf16* g, bf16* l) {
  __builtin_amdgcn_global_load_lds((const __attribute__((address_space(1))) unsigned int*)g,
                                   (__attribute__((address_space(3))) unsigned int*)l, 16, 0, 0);
}

// ============================ router =====================================
__global__ __launch_bounds__(256) void router_kernel(
    const float* __restrict__ x, const int* __restrict__ pids,
    const float* __restrict__ Wr, const float* __restrict__ Wp,
    bf16* __restrict__ xbf, float* __restrict__ gates, int* __restrict__ lists,
    int* __restrict__ counts, float* __restrict__ probSum, float* __restrict__ zSum) {
  __shared__ float xs[32 * 516];     // stride 516: 8 rows/wave land on distinct banks
  __shared__ float wr_s[E_ * 516];   // [e][d], stride 516
  __shared__ float wp_s[E_];
  __shared__ float probAcc[E_];
  __shared__ float zAcc;
  __shared__ int lcnt[E_], lbase[E_];
  __shared__ float lg_s[32][E_ + 1];

  const int tid = threadIdx.x;
  const int tok0 = blockIdx.x * 32;

  // Wr is [D][E] -> wr_s[e*516 + d]
#pragma unroll
  for (int rep = 0; rep < (D_ * E_) / 256; ++rep) {
    int flat = rep * 256 + tid;
    wr_s[(flat & 7) * 516 + (flat >> 3)] = Wr[flat];
  }
  if (tid < E_) {
    wp_s[tid] = Wp[pids[tok0 >> 12] * E_ + tid];  // blocks never straddle batch rows
    probAcc[tid] = 0.f;
    lcnt[tid] = 0;
  }
  if (tid == 0) zAcc = 0.f;

  // stage x tile + write bf16 copy (both coalesced)
  const float4* x4 = (const float4*)(x + (size_t)tok0 * D_);
#pragma unroll
  for (int rep = 0; rep < 16; ++rep) {
    int idx = rep * 256 + tid;  // float4 index in 32x512 tile
    float4 v = x4[idx];
    int t = idx >> 7;           // 128 float4 per row
    int d = (idx & 127) * 4;
    *(float4*)(xs + t * 516 + d) = v;
    union { unsigned short u[4]; uint2 qq; } pk;
    pk.u[0] = __builtin_bit_cast(unsigned short, (bf16)v.x);
    pk.u[1] = __builtin_bit_cast(unsigned short, (bf16)v.y);
    pk.u[2] = __builtin_bit_cast(unsigned short, (bf16)v.z);
    pk.u[3] = __builtin_bit_cast(unsigned short, (bf16)v.w);
    *(uint2*)(xbf + (size_t)tok0 * D_ + (size_t)idx * 4) = pk.qq;
  }
  __syncthreads();

  const int t = tid >> 3, e = tid & 7;
  const int lane = tid & 63;
  {
    float a0 = 0.f, a1 = 0.f, a2 = 0.f, a3 = 0.f;
    const float* xr = xs + t * 516;
    const float* wr = wr_s + e * 516;
#pragma unroll 8
    for (int d = 0; d < D_; d += 4) {
      float4 xv = *(const float4*)(xr + d);
      float4 wv = *(const float4*)(wr + d);
      a0 += xv.x * wv.x;
      a1 += xv.y * wv.y;
      a2 += xv.z * wv.z;
      a3 += xv.w * wv.w;
    }
    lg_s[t][e] = (a0 + a1) + (a2 + a3) + wp_s[e];
  }
  __syncthreads();

  float v[E_];
#pragma unroll
  for (int k = 0; k < E_; ++k) v[k] = lg_s[t][k];
  const float lg = v[e];
  float m = v[0];
#pragma unroll
  for (int k = 1; k < E_; ++k) m = fmaxf(m, v[k]);
  float s = 0.f;
#pragma unroll
  for (int k = 0; k < E_; ++k) s += expf(v[k] - m);
  float prob = expf(lg - m) / s;
  float z = lg * lg;
  // top-2 (ties -> lower index, matching lax.top_k)
  int i1 = 0;
  float v1 = v[0];
#pragma unroll
  for (int k = 1; k < E_; ++k)
    if (v[k] > v1) { v1 = v[k]; i1 = k; }
  int i2 = -1;
  float v2 = -1e30f;
#pragma unroll
  for (int k = 0; k < E_; ++k)
    if (k != i1 && v[k] > v2) { v2 = v[k]; i2 = k; }

  // stats reductions: same-e lanes are stride-8 within the wave
  float p = prob;
  p += __shfl_xor(p, 8);
  p += __shfl_xor(p, 16);
  p += __shfl_xor(p, 32);
  float zz = z;
#pragma unroll
  for (int off = 1; off < 64; off <<= 1) zz += __shfl_xor(zz, off);
  if (lane < 8) atomicAdd(&probAcc[e], p);
  if (lane == 0) atomicAdd(&zAcc, zz);

  // selection + local list append
  int r = (e == i1) ? 0 : ((e == i2) ? 1 : -1);
  int pos = -1;
  if (r >= 0) {
    float ex = expf(v2 - v1);
    float g = (r == 0) ? 1.f / (1.f + ex) : ex / (1.f + ex);
    gates[(tok0 + t) * 2 + r] = g;
    pos = atomicAdd(&lcnt[e], 1);
  }
  __syncthreads();
  if (tid < E_) lbase[tid] = atomicAdd(&counts[tid], lcnt[tid]);
  __syncthreads();
  if (r >= 0) lists[e * NTOK + lbase[e] + pos] = (tok0 + t) * 2 + r;
  if (tid < E_) atomicAdd(&probSum[tid], probAcc[tid]);
  else if (tid == 8) atomicAdd(zSum, zAcc);
}

// ======================= transpose + fp32->bf16 ==========================
// mode < 0: plain transpose. mode >= 0: W13T interleave remap:
// out row = ((h>>4)<<5) | (h&15) | mode  (mode=0 W1, mode=16 W3).
__global__ __launch_bounds__(256) void transpose_convert(const float* __restrict__ in,
                                                         bf16* __restrict__ out, int R, int C,
                                                         size_t out_estride, int mode) {
  const int e = blockIdx.z;
  const int r0 = blockIdx.y * 64, c0 = blockIdx.x * 64;
  in += (size_t)e * R * C;
  out += (size_t)e * out_estride;
  __shared__ unsigned int lt[64 * 33];

  const int tid = threadIdx.x;
  const int m = tid & 15, qq = tid >> 4;
#pragma unroll
  for (int rep = 0; rep < 2; ++rep) {
    int rp = qq + rep * 16;
    const float4 a = *(const float4*)(in + (size_t)(r0 + rp * 2) * C + c0 + m * 4);
    const float4 b = *(const float4*)(in + (size_t)(r0 + rp * 2 + 1) * C + c0 + m * 4);
#pragma unroll
    for (int j = 0; j < 4; ++j) {
      unsigned short lo = __builtin_bit_cast(unsigned short, (bf16)((&a.x)[j]));
      unsigned short hi = __builtin_bit_cast(unsigned short, (bf16)((&b.x)[j]));
      lt[(m * 4 + j) * 33 + rp] = (unsigned int)lo | ((unsigned int)hi << 16);
    }
  }
  __syncthreads();
  const int c = tid >> 2, dw0 = (tid & 3) * 8;
  unsigned int vv[8];
#pragma unroll
  for (int j = 0; j < 8; ++j) vv[j] = lt[c * 33 + dw0 + j];
  int orow = c0 + c;
  if (mode >= 0) orow = ((orow >> 4) << 5) | (orow & 15) | mode;
  uint4* dst = (uint4*)(out + (size_t)orow * R + r0 + dw0 * 2);
  dst[0] = make_uint4(vv[0], vv[1], vv[2], vv[3]);
  dst[1] = make_uint4(vv[4], vv[5], vv[6], vv[7]);
}

// ============================== GEMM1 ====================================
// A-resident grouped GEMM. Block = 64 token-rows (gathered ONCE into 64KB LDS,
// full K=512), 512 threads / 8 waves (each 64Mx64N, acc 4x4 f32x4).
// N-loop: 4 chunks x 512 interleaved cols; per K-step only B is staged
// (R3 2-buf gl16, L2-hot weights), one barrier per step.
// A LDS layout (linear gl16 dest): byte(row,col) = (row>>3)*8192 +
//   (col>>6)*1024 + (row&7)*128 + slot*16, slot = ((col>>3)&7) ^ (row&7);
//   source col pre-permuted by the same XOR -> conflict-free b128 reads.
__global__ __launch_bounds__(512, 2) void gemm1_kernel(
    const bf16* __restrict__ xbf, const bf16* __restrict__ W13T,
    const int* __restrict__ counts, const int* __restrict__ lists,
    const float* __restrict__ gates, bf16* __restrict__ hbuf, int half) {
  const int e = (int)blockIdx.z;
  const int count = counts[e];
  const int m0 = blockIdx.y * 64;
  if (m0 >= count) return;
  int hbase = 0;
  for (int j = 0; j < e; ++j) hbase += counts[j];
  const int* list_e = lists + e * NTOK;
  const bf16* Be = W13T + (size_t)e * (2 * H_) * D_;

  __shared__ bf16 sA[8 * 4096];       // 64 KB: rows m0..m0+63 x K512 (swizzled)
  __shared__ bf16 sB[2 * 512 * 32];   // 64 KB dbuf: chunk rows x 32 K

  const int tid = threadIdx.x;
  const int wave = tid >> 6, lane = tid & 63;
  const int lm = lane & 15, q = lane >> 4;  // q 0..3

  // ---- per-thread gate preload (16 output rows/thread, fixed across chunks)
  float gte[4][4];
#pragma unroll
  for (int mt = 0; mt < 4; ++mt)
#pragma unroll
    for (int r = 0; r < 4; ++r) {
      int grow = m0 + mt * 16 + q * 4 + r;
      gte[mt][r] = (grow < count) ? gates[list_e[grow]] : 0.f;
    }

  // ---- A staging: wave w owns rows w*8..w*8+8, 8 gl16 of 8rows x 64cols
  const int rA = lane >> 3;    // 0..7 row within wave's 8
  const int c16 = lane & 7;    // 16B chunk within 64-col slab
  {
    int rowA = m0 + wave * 8 + rA;
    int prA = (rowA < count) ? list_e[rowA] : 0;
    const bf16* aSrc = xbf + (size_t)(prA >> 1) * D_ + (c16 ^ rA) * 8;
    bf16* aDst = sA + wave * 4096;
#pragma unroll
    for (int j = 0; j < 8; ++j) gl16(aSrc + j * 64, aDst + j * 512);
  }

  // ---- B staging params (proven R3 scheme, 512-row chunks) ----
  const int rsub = lane >> 2, kq = lane & 3;
  const int scol = (kq ^ ((lane >> 3) & 3)) * 8;
  const bf16* bPbase =
      Be + (size_t)(half * (2 * HH) + wave * 64 + rsub) * D_ + scol;
  // stage step s (chunk c=s>>4, t=s&15) into buffer buf
  auto STAGE_B = [&](int s, int buf) {
    int c = s >> 4, t = s & 15;
    size_t off = (size_t)c * 512 * D_ + t * 32;
    bf16* d = sB + buf * 16384 + wave * 2048;
#pragma unroll
    for (int sl = 0; sl < 4; ++sl) gl16(bPbase + off + (size_t)sl * 16 * D_, d + sl * 512);
  };

  // ---- compute addressing ----
  const int r7 = lm & 7;
  int aStat[4];
#pragma unroll
  for (int mt = 0; mt < 4; ++mt)
    aStat[mt] = (mt * 2 + (lm >> 3)) * 8192 + (lm & 7) * 128;  // bytes
  const int rq = (q ^ ((lm >> 1) & 3)) * 8;  // B swizzled read chunk
  const char* aBase = (const char*)sA;

  f32x4 acc[4][4] = {};

  auto COMP = [&](int s, int buf) {
    const int t15 = s & 15;
    const int c64 = (t15 >> 1) * 1024;
    const int cc = (t15 * 4 + q) & 7;
    bf16x8 af[4], bf_[4];
#pragma unroll
    for (int mt = 0; mt < 4; ++mt)
      af[mt] = *(const bf16x8*)(aBase + aStat[mt] + c64 + ((cc ^ r7) << 4));
    const bf16* bR = sB + buf * 16384 + (wave * 64 + lm) * 32 + rq;
#pragma unroll
    for (int nt = 0; nt < 4; ++nt) bf_[nt] = *(const bf16x8*)(bR + nt * 512);
#pragma unroll
    for (int mt = 0; mt < 4; ++mt)
#pragma unroll
      for (int nt = 0; nt < 4; ++nt)
        acc[mt][nt] =
            __builtin_amdgcn_mfma_f32_16x16x32_bf16(af[mt], bf_[nt], acc[mt][nt], 0, 0, 0);
  };

  auto EPI = [&](int c) {
#pragma unroll
    for (int mt = 0; mt < 4; ++mt) {
#pragma unroll
      for (int u = 0; u < 2; ++u) {
#pragma unroll
        for (int r = 0; r < 4; ++r) {
          int grow = m0 + mt * 16 + q * 4 + r;
          if (grow < count) {
            float v1 = acc[mt][2 * u][r];
            float v3 = acc[mt][2 * u + 1][r];
            float g = v1 * (v3 / (1.f + __expf(-v3))) * gte[mt][r];
            hbuf[(size_t)(hbase + grow) * HH + c * 256 + wave * 32 + u * 16 + lm] = (bf16)g;
          }
        }
      }
    }
#pragma unroll
    for (int mt = 0; mt < 4; ++mt)
#pragma unroll
      for (int nt = 0; nt < 4; ++nt)
#pragma unroll
        for (int k2 = 0; k2 < 4; ++k2) acc[mt][nt][k2] = 0.f;
  };

  // ---- prologue: A (once) + B step 0; single drain barrier ----
  STAGE_B(0, 0);
  __syncthreads();

  // ---- unified 64-step loop (4 chunks x 16 K-steps), R3 barrier pattern ----
  for (int ss = 0; ss < 32; ++ss) {
    const int s0 = 2 * ss, s1 = 2 * ss + 1;
    STAGE_B(s1, 1);
    COMP(s0, 0);
    __syncthreads();
    if (s1 < 63) STAGE_B(s1 + 1, 0);
    COMP(s1, 1);
    __syncthreads();
    if ((s1 & 15) == 15) EPI(s1 >> 4);
  }
}

// ============================== GEMM2 ====================================
// y += h-half @ W2e^T[half K-rows]; scatter via atomicAdd. All experts in
// one dispatch per half (z=8). A = packed hbuf rows (contiguous), K=HH.
// R4-proven inner: NBUF=4, stage-first, counted vmcnt(8)/4/0. (R9 verbatim.)
__global__ __launch_bounds__(256, 2) void gemm2_kernel(const bf16* __restrict__ hbuf,
                                                       const bf16* __restrict__ W2T,
                                                       const int* __restrict__ counts,
                                                       const int* __restrict__ lists,
                                                       float* __restrict__ y, int half) {
  const int e = (int)blockIdx.z;
  const int count = counts[e];
  const int m0 = blockIdx.y * 128;
  if (m0 >= count) return;
  int hbase = 0;
  for (int j = 0; j < e; ++j) hbase += counts[j];
  const int n0 = blockIdx.x * 128;  // over D
  const int kb = half * HH;         // K chunk base in W2T cols
  const bf16* W2e = W2T + (size_t)e * D_ * H_;
  const int* list_e = lists + e * NTOK;

  __shared__ bf16 sA[4 * 128 * 32];
  __shared__ bf16 sB[4 * 128 * 32];
  __shared__ int stok[128];

  const int tid = threadIdx.x;
  if (tid < 128) {
    int rg = m0 + tid;
    stok[tid] = (rg < count) ? (list_e[rg] >> 1) : 0;
  }
  __syncthreads();

  const int wave = tid >> 6, lane = tid & 63;
  const int rsub = lane >> 2, kq = lane & 3;
  const int scol = (kq ^ ((lane >> 3) & 3)) * 8;
  const int rA0 = wave * 16 + rsub, rA1 = 64 + wave * 16 + rsub;
  // clamp packed-row reads at buffer end (tail rows of last expert)
  int ra0 = hbase + m0 + rA0;
  int ra1 = hbase + m0 + rA1;
  if (ra0 >= NPAIR) ra0 = NPAIR - 1;
  if (ra1 >= NPAIR) ra1 = NPAIR - 1;
  const bf16* aP0 = hbuf + (size_t)ra0 * HH + scol;
  const bf16* aP1 = hbuf + (size_t)ra1 * HH + scol;
  const bf16* bP0 = W2e + (size_t)(n0 + rA0) * H_ + kb + scol;
  const bf16* bP1 = W2e + (size_t)(n0 + rA1) * H_ + kb + scol;

  const int wm = wave >> 1, wn = wave & 1;
  const int lm = lane & 15, q = lane >> 4;
  const int rq = (q ^ ((lm >> 1) & 3)) * 8;
  const bf16* aRd = sA + (wm * 64 + lm) * 32 + rq;
  const bf16* bRd = sB + (wn * 64 + lm) * 32 + rq;

  f32x4 acc[4][4] = {};

  auto STAGE = [&](int t, int bi) {
    const int ko = t * 32;
    bf16* ba = sA + bi * 4096;
    bf16* bb = sB + bi * 4096;
    gl16(aP0 + ko, ba + wave * 512);
    gl16(aP1 + ko, ba + (wave + 4) * 512);
    gl16(bP0 + ko, bb + wave * 512);
    gl16(bP1 + ko, bb + (wave + 4) * 512);
  };
  auto COMP = [&](int bi) {
    const bf16* aR = aRd + bi * 4096;
    const bf16* bR = bRd + bi * 4096;
    bf16x8 af[4], bf_[4];
#pragma unroll
    for (int i = 0; i < 4; ++i) {
      af[i] = *(const bf16x8*)(aR + i * 512);
      bf_[i] = *(const bf16x8*)(bR + i * 512);
    }
#pragma unroll
    for (int mt = 0; mt < 4; ++mt)
#pragma unroll
      for (int nt = 0; nt < 4; ++nt)
        acc[mt][nt] =
            __builtin_amdgcn_mfma_f32_16x16x32_bf16(af[mt], bf_[nt], acc[mt][nt], 0, 0, 0);
  };

  const int NT = HH / 32;  // 32
  STAGE(0, 0);
  STAGE(1, 1);
  for (int t = 0; t < NT - 2; ++t) {
    STAGE(t + 2, (t + 2) & 3);
    asm volatile("s_waitcnt vmcnt(8) lgkmcnt(0)" ::: "memory");
    __builtin_amdgcn_s_barrier();
    COMP(t & 3);
  }
  asm volatile("s_waitcnt vmcnt(4) lgkmcnt(0)" ::: "memory");
  __builtin_amdgcn_s_barrier();
  COMP((NT - 2) & 3);
  asm volatile("s_waitcnt vmcnt(0) lgkmcnt(0)" ::: "memory");
  __builtin_amdgcn_s_barrier();
  COMP((NT - 1) & 3);

#pragma unroll
  for (int mt = 0; mt < 4; ++mt) {
#pragma unroll
    for (int nt = 0; nt < 4; ++nt) {
#pragma unroll
      for (int r = 0; r < 4; ++r) {
        int lrow = wm * 64 + mt * 16 + q * 4 + r;
        int grow = m0 + lrow;
        if (grow < count) {
          atomicAdd(&y[(size_t)stok[lrow] * D_ + n0 + wn * 64 + nt * 16 + lm], acc[mt][nt][r]);
        }
      }
    }
  }
}

// ============================= finalize ==================================
__global__ __launch_bounds__(256) void finalize_kernel(const float* __restrict__ Wp,
                                                       const float* __restrict__ probSum,
                                                       const float* __restrict__ zSum,
                                                       float* __restrict__ out) {
  __shared__ float pn[P_][E_];
  __shared__ float simAcc;
  const int tid = threadIdx.x;
  if (tid == 0) simAcc = 0.f;
  if (tid < P_) {
    float v[E_], m = -1e30f, s = 0.f;
#pragma unroll
    for (int e = 0; e < E_; ++e) {
      v[e] = Wp[tid * E_ + e];
      m = fmaxf(m, v[e]);
    }
#pragma unroll
    for (int e = 0; e < E_; ++e) {
      float ex = expf(v[e] - m);
      pn[tid][e] = ex;
      s += ex;
    }
#pragma unroll
    for (int e = 0; e < E_; ++e) pn[tid][e] /= s;
  }
  __syncthreads();
  {
    int i = tid >> 4, j = tid & 15;
    if (i != j) {
      float d = 0.f;
#pragma unroll
      for (int e = 0; e < E_; ++e) d += pn[i][e] * pn[j][e];
      atomicAdd(&simAcc, d);
    }
  }
  __syncthreads();
  if (tid == 0) {
    out[0] = zSum[0] / (float)(NTOK * E_) * 0.001f;
    float bl = 0.f;
#pragma unroll
    for (int e = 0; e < E_; ++e) {
      float pm = probSum[e] / (float)NTOK - 1.f / (float)E_;
      bl += pm * pm;
    }
    out[1] = bl / (float)E_;
    out[2] = simAcc / (float)(P_ * P_) * 0.1f;
  }
}

// ============================== launch ===================================
extern "C" void kernel_launch(void* const* d_in, const int* in_sizes, int n_in, void* d_out,
                              int out_size, void* d_ws, size_t ws_size, hipStream_t stream) {
  const float* x = (const float*)d_in[0];
  const int* pids = (const int*)d_in[1];
  const float* Wr = (const float*)d_in[2];
  const float* Wp = (const float*)d_in[3];
  const float* W1 = (const float*)d_in[4];
  const float* W2 = (const float*)d_in[5];
  const float* W3 = (const float*)d_in[6];
  float* y = (float*)d_out;

  if (ws_size < WS_NEEDED) return;

  char* ws = (char*)d_ws;
  int* counts = (int*)ws;
  float* probSum = (float*)(ws + 32);
  float* zSum = (float*)(ws + 64);
  float* gates = (float*)(ws + OFF_GATES);
  int* lists = (int*)(ws + OFF_LIST);
  bf16* xbf = (bf16*)(ws + OFF_XBF);
  bf16* W13T = (bf16*)(ws + OFF_W13T);
  bf16* W2T = (bf16*)(ws + OFF_W2T);
  bf16* hbuf = (bf16*)(ws + OFF_HBUF);

  hipMemsetAsync(ws, 0, 256, stream);
  hipMemsetAsync(d_out, 0, (size_t)NTOK * D_ * 4, stream);

  router_kernel<<<dim3(NTOK / 32), 256, 0, stream>>>(x, pids, Wr, Wp, xbf, gates, lists, counts,
                                                     probSum, zSum);
  // W1 -> even 16-col groups, W3 -> odd 16-col groups of W13T [E][2H][D]
  transpose_convert<<<dim3(H_ / 64, D_ / 64, E_), 256, 0, stream>>>(W1, W13T, D_, H_,
                                                                    (size_t)2 * H_ * D_, 0);
  transpose_convert<<<dim3(H_ / 64, D_ / 64, E_), 256, 0, stream>>>(W3, W13T, D_, H_,
                                                                    (size_t)2 * H_ * D_, 16);
  transpose_convert<<<dim3(D_ / 64, H_ / 64, E_), 256, 0, stream>>>(W2, W2T, H_, D_,
                                                                    (size_t)H_ * D_, -1);

  for (int half = 0; half < 2; ++half) {
    gemm1_kernel<<<dim3(1, NTOK / 64, E_), 512, 0, stream>>>(xbf, W13T, counts, lists, gates,
                                                             hbuf, half);
    gemm2_kernel<<<dim3(D_ / 128, NTOK / 128, E_), 256, 0, stream>>>(hbuf, W2T, counts, lists,
                                                                     y, half);
  }
  finalize_kernel<<<1, 256, 0, stream>>>(Wp, probSum, zSum, y + (size_t)NTOK * D_);
}